// Round 6
// baseline (284.799 us; speedup 1.0000x reference)
//
#include <hip/hip_runtime.h>
#include <hip/hip_bf16.h>

// Algebra: softmax(QK^T*c) with Q=xWq+bq, K=xWk+bk. Row-constant logit terms
// cancel in softmax, so QK^T ~ x(WqWk^T)x^T + beta_m, beta = x(Wk bq).
// => never materialize q,k: S = xg @ xb^T with xg = xb @ (WkWq^T)^T.
// With the given zero biases beta==0, but it is computed exactly anyway.

// ---------- helpers ----------

typedef __attribute__((ext_vector_type(8))) short bf16x8;
typedef __attribute__((ext_vector_type(4))) float f32x4;

#define AS_G(p) ((__attribute__((address_space(1))) void*)(p))
#define AS_L(p) ((__attribute__((address_space(3))) void*)(p))

__device__ __forceinline__ unsigned short f2bf(float f) {
  unsigned int u = __float_as_uint(f);
  unsigned int lsb = (u >> 16) & 1u;
  u += 0x7fffu + lsb;
  return (unsigned short)(u >> 16);
}

__device__ __forceinline__ float bf2f(unsigned short h) {
  return __uint_as_float(((unsigned int)h) << 16);
}

// ---------- BK=64 NT GEMM core: C = A * B^T ----------
// 128x128 tile, BK=64, 256 threads = 4 waves x (64x64 = 4x4 MFMA 16x16x32).
// LDS slot s of row r holds global k-chunk s ^ (r&7): measured 0 bank conflicts.
//
// EPI=1: QK: P' = bf16(exp(acc*scale + sbeta[col])), atomic rsum row sums.
// EPI=3: PV: out fp32 = acc / rsum[row].
// EPI=4: plain bf16 C (for the GT = WkWq^T constant GEMM).
// EPI=5: fused proj: col seg 0 -> xg bf16, seg 1 -> vt TRANSPOSED (+bv).

template <int EPI>
__global__ __launch_bounds__(256) void gemm64(
    const unsigned short* __restrict__ A, const unsigned short* __restrict__ B,
    float* __restrict__ Cf, long long sA, long long sB, long long sC,
    int K, int lda, int ldb, int ldc,
    unsigned short* __restrict__ u0, unsigned short* __restrict__ u1,
    const float* __restrict__ f0, const float* __restrict__ f1,
    float* __restrict__ rsum, float scale)
{
  __shared__ unsigned short lA[128 * 64];
  __shared__ unsigned short lB[128 * 64];

  const int t = threadIdx.x;
  const int rowBase = blockIdx.y * 128;
  const int colBase = blockIdx.x * 128;
  A += (long long)blockIdx.z * sA;
  B += (long long)blockIdx.z * sB;

  const int l = t & 63;
  const int w = t >> 6;
  const int wrow = (w >> 1) * 64;
  const int wcol = (w & 1) * 64;
  const int q = l >> 4;
  const int r16 = l & 15;

  f32x4 acc[4][4] = {};

  const int r0 = t >> 3;
  const int goff = (((t & 7) ^ (r0 & 7)) << 3);

  for (int kt = 0; kt < K; kt += 64) {
    __syncthreads();
#pragma unroll
    for (int u = 0; u < 4; u++) {
      const int row = r0 + 32 * u;
      __builtin_amdgcn_global_load_lds(AS_G(A + (size_t)(rowBase + row) * lda + kt + goff),
                                       AS_L(lA + (t + 256 * u) * 8), 16, 0, 0);
      __builtin_amdgcn_global_load_lds(AS_G(B + (size_t)(colBase + row) * ldb + kt + goff),
                                       AS_L(lB + (t + 256 * u) * 8), 16, 0, 0);
    }
    __syncthreads();

#pragma unroll
    for (int ks = 0; ks < 2; ks++) {
      bf16x8 af[4], bfr[4];
#pragma unroll
      for (int i = 0; i < 4; i++) {
        const int s = ((ks * 4 + q) ^ (r16 & 7));
        af[i] = *(const bf16x8*)(lA + (wrow + i * 16 + r16) * 64 + s * 8);
      }
#pragma unroll
      for (int j = 0; j < 4; j++) {
        const int s = ((ks * 4 + q) ^ (r16 & 7));
        bfr[j] = *(const bf16x8*)(lB + (wcol + j * 16 + r16) * 64 + s * 8);
      }
#pragma unroll
      for (int i = 0; i < 4; i++)
#pragma unroll
        for (int j = 0; j < 4; j++)
          acc[i][j] = __builtin_amdgcn_mfma_f32_16x16x32_bf16(af[i], bfr[j], acc[i][j], 0, 0, 0);
    }
  }

  // epilogues: C layout row=(lane>>4)*4+r, col=lane&15 (m89/m91 verified)
  if (EPI == 1) {
    unsigned short* p16 = u0 + (long long)blockIdx.z * sC;
    float* rs = rsum + ((long long)blockIdx.z << 11);
    const float* sb = f0 + ((long long)blockIdx.z << 11);
#pragma unroll
    for (int i = 0; i < 4; i++) {
#pragma unroll
      for (int r = 0; r < 4; r++) {
        int row = rowBase + wrow + i * 16 + q * 4 + r;
        float rowpart = 0.f;
#pragma unroll
        for (int j = 0; j < 4; j++) {
          int col = colBase + wcol + j * 16 + r16;
          float e = __expf(acc[i][j][r] * scale + sb[col]);
          p16[(size_t)row * ldc + col] = f2bf(e);
          rowpart += e;
        }
#pragma unroll
        for (int m = 1; m < 16; m <<= 1) rowpart += __shfl_xor(rowpart, m);
        if (r16 == 0) atomicAdd(rs + row, rowpart);
      }
    }
  } else if (EPI == 3) {
    float* C = Cf + (long long)blockIdx.z * sC;
    const float* rs = rsum + ((long long)blockIdx.z << 11);
#pragma unroll
    for (int i = 0; i < 4; i++) {
#pragma unroll
      for (int r = 0; r < 4; r++) {
        int row = rowBase + wrow + i * 16 + q * 4 + r;
        float inv = 1.0f / rs[row];
#pragma unroll
        for (int j = 0; j < 4; j++) {
          int col = colBase + wcol + j * 16 + r16;
          C[(size_t)row * ldc + col] = acc[i][j][r] * inv;
        }
      }
    }
  } else if (EPI == 4) {
#pragma unroll
    for (int i = 0; i < 4; i++) {
#pragma unroll
      for (int r = 0; r < 4; r++) {
        int row = rowBase + wrow + i * 16 + q * 4 + r;
#pragma unroll
        for (int j = 0; j < 4; j++) {
          int col = colBase + wcol + j * 16 + r16;
          u0[(size_t)row * ldc + col] = f2bf(acc[i][j][r]);
        }
      }
    }
  } else {  // EPI == 5: fused [xG | v] projection
    if (colBase < 1024) {
#pragma unroll
      for (int i = 0; i < 4; i++) {
#pragma unroll
        for (int r = 0; r < 4; r++) {
          int row = rowBase + wrow + i * 16 + q * 4 + r;
#pragma unroll
          for (int j = 0; j < 4; j++) {
            int col = colBase + wcol + j * 16 + r16;
            u0[(size_t)row * 1024 + col] = f2bf(acc[i][j][r]);
          }
        }
      }
    } else {
      const int ob = colBase - 1024;
#pragma unroll
      for (int i = 0; i < 4; i++) {
        int posBase = rowBase + wrow + i * 16 + q * 4;
        int b = posBase >> 11;
        int pos = posBase & 2047;
#pragma unroll
        for (int j = 0; j < 4; j++) {
          int o = ob + wcol + j * 16 + r16;
          float bias = f1[o];
          ushort4 pk;
          pk.x = f2bf(acc[i][j][0] + bias);
          pk.y = f2bf(acc[i][j][1] + bias);
          pk.z = f2bf(acc[i][j][2] + bias);
          pk.w = f2bf(acc[i][j][3] + bias);
          *(ushort4*)(u1 + ((size_t)((b << 10) + o) * 2048 + pos)) = pk;
        }
      }
    }
  }
}

// ---------- prep: cast x, Wq, Wk to bf16; zero rsum ----------

__global__ __launch_bounds__(256) void prep(
    const float* __restrict__ x, unsigned short* __restrict__ xb,
    const float* __restrict__ Wq, unsigned short* __restrict__ wqb,
    const float* __restrict__ Wk, unsigned short* __restrict__ wkb,
    float* __restrict__ rsum)
{
  int i = blockIdx.x * 256 + threadIdx.x;
  if (i < 2097152) {
    float4 v = ((const float4*)x)[i];
    ushort4 o;
    o.x = f2bf(v.x); o.y = f2bf(v.y); o.z = f2bf(v.z); o.w = f2bf(v.w);
    ((ushort4*)xb)[i] = o;
  }
  if (i < 262144) {
    float4 v = ((const float4*)Wq)[i];
    ushort4 o;
    o.x = f2bf(v.x); o.y = f2bf(v.y); o.z = f2bf(v.z); o.w = f2bf(v.w);
    ((ushort4*)wqb)[i] = o;
    float4 u = ((const float4*)Wk)[i];
    ushort4 p;
    p.x = f2bf(u.x); p.y = f2bf(u.y); p.z = f2bf(u.z); p.w = f2bf(u.w);
    ((ushort4*)wkb)[i] = p;
  }
  if (i < 2048) ((float4*)rsum)[i] = make_float4(0.f, 0.f, 0.f, 0.f);
}

// ---------- Wv transpose: dst[o, d] = bf16(Wv[d, o]) ----------

__global__ __launch_bounds__(256) void wtrans(
    const float* __restrict__ Wv, unsigned short* __restrict__ dst)
{
  __shared__ float tile[32][33];
  const int bc = blockIdx.x * 32;  // o
  const int br = blockIdx.y * 32;  // d
  const int tx = threadIdx.x;
  const int ty = threadIdx.y;
#pragma unroll
  for (int i = 0; i < 4; i++)
    tile[ty + i * 8][tx] = Wv[(size_t)(br + ty + i * 8) * 1024 + bc + tx];
  __syncthreads();
#pragma unroll
  for (int i = 0; i < 4; i++)
    dst[(size_t)(bc + ty + i * 8) * 1024 + br + tx] = f2bf(tile[tx][ty + i * 8]);
}

// ---------- bias-correction matvecs (exact handling of bq; zero here) ----------

// z[d] = sum_h Wk[d,h] * bq[h]       (one wave per output)
__global__ __launch_bounds__(256) void matvec_wb(
    const float* __restrict__ Wk, const float* __restrict__ bq,
    float* __restrict__ z)
{
  int w = threadIdx.x >> 6, l = threadIdx.x & 63;
  int d = blockIdx.x * 4 + w;
  const float* row = Wk + (size_t)d * 1024;
  float s = 0.f;
  for (int h = l; h < 1024; h += 64) s += row[h] * bq[h];
#pragma unroll
  for (int off = 32; off >= 1; off >>= 1) s += __shfl_xor(s, off);
  if (l == 0) z[d] = s;
}

// sbeta[m] = scale * sum_d xb[m,d] * z[d]
__global__ __launch_bounds__(256) void matvec_xz(
    const unsigned short* __restrict__ xb, const float* __restrict__ z,
    float* __restrict__ sbeta, float scale)
{
  int w = threadIdx.x >> 6, l = threadIdx.x & 63;
  int m = blockIdx.x * 4 + w;
  const unsigned short* row = xb + (size_t)m * 1024;
  float s = 0.f;
  for (int h = l; h < 1024; h += 64) s += bf2f(row[h]) * z[h];
#pragma unroll
  for (int off = 32; off >= 1; off >>= 1) s += __shfl_xor(s, off);
  if (l == 0) sbeta[m] = s * scale;
}

// ---------- driver ----------

extern "C" void kernel_launch(void* const* d_in, const int* in_sizes, int n_in,
                              void* d_out, int out_size, void* d_ws, size_t ws_size,
                              hipStream_t stream) {
  (void)in_sizes; (void)n_in; (void)out_size;

  const float* x  = (const float*)d_in[0];
  const float* Wq = (const float*)d_in[1];
  const float* bq = (const float*)d_in[2];
  const float* Wk = (const float*)d_in[3];
  // bk unused: (xWq+bq)bk^T is row-constant in the logits -> cancels in softmax
  const float* Wv = (const float*)d_in[5];
  const float* bv = (const float*)d_in[6];
  float* out = (float*)d_out;

  const int Nb = 4, L = 2048, D = 1024, O = 1024;
  const int M = Nb * L;  // 8192
  const float scale = 0.022097086912079608f;  // 1/sqrt(2048)

  char* ws = (char*)d_ws;
  size_t off = 0;
  unsigned short* xb  = (unsigned short*)(ws + off); off += (size_t)M * D * 2;
  unsigned short* xg  = (unsigned short*)(ws + off); off += (size_t)M * D * 2;
  unsigned short* vt  = (unsigned short*)(ws + off); off += (size_t)M * O * 2;
  unsigned short* Bp  = (unsigned short*)(ws + off); off += (size_t)2048 * D * 2; // [GT; WvT]
  unsigned short* wqb = (unsigned short*)(ws + off); off += (size_t)D * D * 2;
  unsigned short* wkb = (unsigned short*)(ws + off); off += (size_t)D * D * 2;
  unsigned short* P   = (unsigned short*)(ws + off); off += (size_t)Nb * L * L * 2;
  float* rsum  = (float*)(ws + off); off += (size_t)M * 4;
  float* zvec  = (float*)(ws + off); off += (size_t)D * 4;
  float* sbeta = (float*)(ws + off); off += (size_t)M * 4;
  if (ws_size < off) return;

  dim3 blk256(256);

  // casts + rsum zero
  prep<<<8192, blk256, 0, stream>>>(x, xb, Wq, wqb, Wk, wkb, rsum);

  // Bp rows 1024..2047 = Wv^T
  wtrans<<<dim3(32, 32, 1), dim3(32, 8), 0, stream>>>(Wv, Bp + (size_t)1024 * 1024);

  // z = Wk @ bq  (exact bias term; zero with these inputs)
  matvec_wb<<<256, blk256, 0, stream>>>(Wk, bq, zvec);

  // Bp rows 0..1023 = GT = Wk @ Wq^T = (WqWk^T)^T
  gemm64<4><<<dim3(8, 8, 1), blk256, 0, stream>>>(
      wkb, wqb, nullptr, 0, 0, 0, D, D, D, D,
      Bp, nullptr, nullptr, nullptr, nullptr, 0.f);

  // sbeta = scale * (xb @ z)
  matvec_xz<<<2048, blk256, 0, stream>>>(xb, zvec, sbeta, scale);

  // fused: [xg | v] = xb @ Bp^T ; xg plain bf16, v -> vt transposed (+bv)
  gemm64<5><<<dim3(16, 64, 1), blk256, 0, stream>>>(
      xb, Bp, nullptr, 0, 0, 0, D, D, D, 0,
      xg, vt, nullptr, bv, nullptr, 0.f);

  // QK: P'[b] = exp(xg[b] @ xb[b]^T * scale + sbeta), rsum = row sums
  gemm64<1><<<dim3(16, 16, 4), blk256, 0, stream>>>(
      xg, xb, nullptr, (long long)L * D, (long long)L * D, (long long)L * L,
      D, D, D, L,
      P, nullptr, sbeta, nullptr, rsum, scale);

  // PV: out[b] = (P'[b] @ vt[b]^T) / rsum
  gemm64<3><<<dim3(8, 16, 4), blk256, 0, stream>>>(
      P, vt, out, (long long)L * L, (long long)O * L, (long long)L * O,
      L, L, L, O,
      nullptr, nullptr, nullptr, nullptr, rsum, 0.f);
}

// Round 7
// 275.143 us; speedup vs baseline: 1.0351x; 1.0351x over previous
//
#include <hip/hip_runtime.h>
#include <hip/hip_bf16.h>

// Algebra: softmax(QK^T*c) with Q=xWq+bq, K=xWk+bk. Row-constant logit terms
// cancel in softmax => S ~ x(WqWk^T)x^T + beta_m, beta = x(Wk bq).
// Never materialize q,k: xg = xb @ GT^T (GT = Wk Wq^T), S = xg @ xb^T.
// Launch-count is the scarce resource (~10us serialized gap per launch,
// measured round 6): 5 launches total.

// ---------- helpers ----------

typedef __attribute__((ext_vector_type(8))) short bf16x8;
typedef __attribute__((ext_vector_type(4))) float f32x4;

#define AS_G(p) ((__attribute__((address_space(1))) void*)(p))
#define AS_L(p) ((__attribute__((address_space(3))) void*)(p))

__device__ __forceinline__ unsigned short f2bf(float f) {
  unsigned int u = __float_as_uint(f);
  unsigned int lsb = (u >> 16) & 1u;
  u += 0x7fffu + lsb;
  return (unsigned short)(u >> 16);
}

__device__ __forceinline__ float bf2f(unsigned short h) {
  return __uint_as_float(((unsigned int)h) << 16);
}

// ---------- BK=64 NT GEMM core: C = A * B^T ----------
// 128x128 tile, BK=64, 256 threads = 4 waves x (64x64 = 4x4 MFMA 16x16x32).
// LDS slot s of row r holds global k-chunk s ^ (r&7): measured 0 conflicts.
//
// EPI=1: QK: P' = bf16(exp(acc*scale + sbeta[col])), atomic rsum row sums.
// EPI=3: PV: out fp32 = acc / rsum[row].
// EPI=5: fused proj: col seg 0 -> xg bf16, seg 1 -> vt TRANSPOSED (+bv).

template <int EPI>
__global__ __launch_bounds__(256) void gemm64(
    const unsigned short* __restrict__ A, const unsigned short* __restrict__ B,
    float* __restrict__ Cf, long long sA, long long sB, long long sC,
    int K, int lda, int ldb, int ldc,
    unsigned short* __restrict__ u0, unsigned short* __restrict__ u1,
    const float* __restrict__ f0, const float* __restrict__ f1,
    float* __restrict__ rsum, float scale)
{
  __shared__ unsigned short lA[128 * 64];
  __shared__ unsigned short lB[128 * 64];

  const int t = threadIdx.x;
  const int rowBase = blockIdx.y * 128;
  const int colBase = blockIdx.x * 128;
  A += (long long)blockIdx.z * sA;
  B += (long long)blockIdx.z * sB;

  const int l = t & 63;
  const int w = t >> 6;
  const int wrow = (w >> 1) * 64;
  const int wcol = (w & 1) * 64;
  const int q = l >> 4;
  const int r16 = l & 15;

  f32x4 acc[4][4] = {};

  const int r0 = t >> 3;
  const int goff = (((t & 7) ^ (r0 & 7)) << 3);

  for (int kt = 0; kt < K; kt += 64) {
    __syncthreads();
#pragma unroll
    for (int u = 0; u < 4; u++) {
      const int row = r0 + 32 * u;
      __builtin_amdgcn_global_load_lds(AS_G(A + (size_t)(rowBase + row) * lda + kt + goff),
                                       AS_L(lA + (t + 256 * u) * 8), 16, 0, 0);
      __builtin_amdgcn_global_load_lds(AS_G(B + (size_t)(colBase + row) * ldb + kt + goff),
                                       AS_L(lB + (t + 256 * u) * 8), 16, 0, 0);
    }
    __syncthreads();

#pragma unroll
    for (int ks = 0; ks < 2; ks++) {
      bf16x8 af[4], bfr[4];
#pragma unroll
      for (int i = 0; i < 4; i++) {
        const int s = ((ks * 4 + q) ^ (r16 & 7));
        af[i] = *(const bf16x8*)(lA + (wrow + i * 16 + r16) * 64 + s * 8);
      }
#pragma unroll
      for (int j = 0; j < 4; j++) {
        const int s = ((ks * 4 + q) ^ (r16 & 7));
        bfr[j] = *(const bf16x8*)(lB + (wcol + j * 16 + r16) * 64 + s * 8);
      }
#pragma unroll
      for (int i = 0; i < 4; i++)
#pragma unroll
        for (int j = 0; j < 4; j++)
          acc[i][j] = __builtin_amdgcn_mfma_f32_16x16x32_bf16(af[i], bfr[j], acc[i][j], 0, 0, 0);
    }
  }

  // epilogues: C layout row=(lane>>4)*4+r, col=lane&15 (m89/m91 verified)
  if (EPI == 1) {
    unsigned short* p16 = u0 + (long long)blockIdx.z * sC;
    float* rs = rsum + ((long long)blockIdx.z << 11);
    const float* sb = f0 + ((long long)blockIdx.z << 11);
#pragma unroll
    for (int i = 0; i < 4; i++) {
#pragma unroll
      for (int r = 0; r < 4; r++) {
        int row = rowBase + wrow + i * 16 + q * 4 + r;
        float rowpart = 0.f;
#pragma unroll
        for (int j = 0; j < 4; j++) {
          int col = colBase + wcol + j * 16 + r16;
          float e = __expf(acc[i][j][r] * scale + sb[col]);
          p16[(size_t)row * ldc + col] = f2bf(e);
          rowpart += e;
        }
#pragma unroll
        for (int m = 1; m < 16; m <<= 1) rowpart += __shfl_xor(rowpart, m);
        if (r16 == 0) atomicAdd(rs + row, rowpart);
      }
    }
  } else if (EPI == 3) {
    float* C = Cf + (long long)blockIdx.z * sC;
    const float* rs = rsum + ((long long)blockIdx.z << 11);
#pragma unroll
    for (int i = 0; i < 4; i++) {
#pragma unroll
      for (int r = 0; r < 4; r++) {
        int row = rowBase + wrow + i * 16 + q * 4 + r;
        float inv = 1.0f / rs[row];
#pragma unroll
        for (int j = 0; j < 4; j++) {
          int col = colBase + wcol + j * 16 + r16;
          C[(size_t)row * ldc + col] = acc[i][j][r] * inv;
        }
      }
    }
  } else {  // EPI == 5: fused [xG | v] projection
    if (colBase < 1024) {
#pragma unroll
      for (int i = 0; i < 4; i++) {
#pragma unroll
        for (int r = 0; r < 4; r++) {
          int row = rowBase + wrow + i * 16 + q * 4 + r;
#pragma unroll
          for (int j = 0; j < 4; j++) {
            int col = colBase + wcol + j * 16 + r16;
            u0[(size_t)row * 1024 + col] = f2bf(acc[i][j][r]);
          }
        }
      }
    } else {
      const int ob = colBase - 1024;
#pragma unroll
      for (int i = 0; i < 4; i++) {
        int posBase = rowBase + wrow + i * 16 + q * 4;
        int b = posBase >> 11;
        int pos = posBase & 2047;
#pragma unroll
        for (int j = 0; j < 4; j++) {
          int o = ob + wcol + j * 16 + r16;
          float bias = f1[o];
          ushort4 pk;
          pk.x = f2bf(acc[i][j][0] + bias);
          pk.y = f2bf(acc[i][j][1] + bias);
          pk.z = f2bf(acc[i][j][2] + bias);
          pk.w = f2bf(acc[i][j][3] + bias);
          *(ushort4*)(u1 + ((size_t)((b << 10) + o) * 2048 + pos)) = pk;
        }
      }
    }
  }
}

// ---------- prep_all: one launch for every independent small op ----------
// blocks [0,8192):       xb = bf16(x)                    (2.1M float4s)
// blocks [8192,9216):    wqb = bf16(Wq)
// blocks [9216,10240):   wkb = bf16(Wk)
// blocks [10240,11264):  Bp[1024..2047] = bf16(Wv^T)     (32x32 LDS tiles)
// blocks [11264,11520):  zvec = Wk @ bq                  (4 waves = 4 rows)
// blocks [11520,11528):  rsum = 0

__global__ __launch_bounds__(256) void prep_all(
    const float* __restrict__ x, unsigned short* __restrict__ xb,
    const float* __restrict__ Wq, unsigned short* __restrict__ wqb,
    const float* __restrict__ Wk, unsigned short* __restrict__ wkb,
    const float* __restrict__ Wv, unsigned short* __restrict__ wvt,
    const float* __restrict__ bq, float* __restrict__ zvec,
    float* __restrict__ rsum)
{
  __shared__ float tile[32][33];
  const int b = blockIdx.x;
  const int t = threadIdx.x;

  if (b < 8192) {
    int i = b * 256 + t;
    float4 v = ((const float4*)x)[i];
    ushort4 o;
    o.x = f2bf(v.x); o.y = f2bf(v.y); o.z = f2bf(v.z); o.w = f2bf(v.w);
    ((ushort4*)xb)[i] = o;
  } else if (b < 9216) {
    int i = (b - 8192) * 256 + t;
    float4 v = ((const float4*)Wq)[i];
    ushort4 o;
    o.x = f2bf(v.x); o.y = f2bf(v.y); o.z = f2bf(v.z); o.w = f2bf(v.w);
    ((ushort4*)wqb)[i] = o;
  } else if (b < 10240) {
    int i = (b - 9216) * 256 + t;
    float4 v = ((const float4*)Wk)[i];
    ushort4 o;
    o.x = f2bf(v.x); o.y = f2bf(v.y); o.z = f2bf(v.z); o.w = f2bf(v.w);
    ((ushort4*)wkb)[i] = o;
  } else if (b < 11264) {
    int idx = b - 10240;
    const int bc = (idx & 31) * 32;   // o
    const int br = (idx >> 5) * 32;   // d
    const int tx = t & 31;
    const int ty = t >> 5;            // 0..7
#pragma unroll
    for (int i = 0; i < 4; i++)
      tile[ty + i * 8][tx] = Wv[(size_t)(br + ty + i * 8) * 1024 + bc + tx];
    __syncthreads();
#pragma unroll
    for (int i = 0; i < 4; i++)
      wvt[(size_t)(bc + ty + i * 8) * 1024 + br + tx] = f2bf(tile[tx][ty + i * 8]);
  } else if (b < 11520) {
    int w = t >> 6, l = t & 63;
    int d = (b - 11264) * 4 + w;
    const float* row = Wk + (size_t)d * 1024;
    float s = 0.f;
    for (int h = l; h < 1024; h += 64) s += row[h] * bq[h];
#pragma unroll
    for (int off = 32; off >= 1; off >>= 1) s += __shfl_xor(s, off);
    if (l == 0) zvec[d] = s;
  } else {
    int i = (b - 11520) * 256 + t;
    ((float4*)rsum)[i] = make_float4(0.f, 0.f, 0.f, 0.f);
  }
}

// ---------- gt_sbeta: GT tiles + sbeta matvec in one launch ----------
// blocks [0,64):   GT = wkb @ wqb^T (NT, bf16 out into Bp rows 0..1023)
// blocks [64,576): sbeta[m] = scale * sum_d xb[m,d]*zvec[d], 16 rows/block

__global__ __launch_bounds__(256) void gt_sbeta(
    const unsigned short* __restrict__ wkb, const unsigned short* __restrict__ wqb,
    unsigned short* __restrict__ gt,
    const unsigned short* __restrict__ xb, const float* __restrict__ zvec,
    float* __restrict__ sbeta, float scale)
{
  __shared__ unsigned short lA[128 * 64];
  __shared__ unsigned short lB[128 * 64];

  const int t = threadIdx.x;
  const int bid = blockIdx.x;

  if (bid >= 64) {
    // sbeta part
    int w = t >> 6, l = t & 63;
    int rowBase = (bid - 64) * 16 + w * 4;
#pragma unroll
    for (int rr = 0; rr < 4; rr++) {
      int m = rowBase + rr;
      const unsigned short* row = xb + (size_t)m * 1024;
      float s = 0.f;
      for (int h = l; h < 1024; h += 64) s += bf2f(row[h]) * zvec[h];
#pragma unroll
      for (int off = 32; off >= 1; off >>= 1) s += __shfl_xor(s, off);
      if (l == 0) sbeta[m] = s * scale;
    }
    return;
  }

  const int rowBase = (bid >> 3) * 128;
  const int colBase = (bid & 7) * 128;
  const int l = t & 63;
  const int w = t >> 6;
  const int wrow = (w >> 1) * 64;
  const int wcol = (w & 1) * 64;
  const int q = l >> 4;
  const int r16 = l & 15;

  f32x4 acc[4][4] = {};
  const int r0 = t >> 3;
  const int goff = (((t & 7) ^ (r0 & 7)) << 3);

  for (int kt = 0; kt < 1024; kt += 64) {
    __syncthreads();
#pragma unroll
    for (int u = 0; u < 4; u++) {
      const int row = r0 + 32 * u;
      __builtin_amdgcn_global_load_lds(AS_G(wkb + (size_t)(rowBase + row) * 1024 + kt + goff),
                                       AS_L(lA + (t + 256 * u) * 8), 16, 0, 0);
      __builtin_amdgcn_global_load_lds(AS_G(wqb + (size_t)(colBase + row) * 1024 + kt + goff),
                                       AS_L(lB + (t + 256 * u) * 8), 16, 0, 0);
    }
    __syncthreads();

#pragma unroll
    for (int ks = 0; ks < 2; ks++) {
      bf16x8 af[4], bfr[4];
#pragma unroll
      for (int i = 0; i < 4; i++) {
        const int s = ((ks * 4 + q) ^ (r16 & 7));
        af[i] = *(const bf16x8*)(lA + (wrow + i * 16 + r16) * 64 + s * 8);
      }
#pragma unroll
      for (int j = 0; j < 4; j++) {
        const int s = ((ks * 4 + q) ^ (r16 & 7));
        bfr[j] = *(const bf16x8*)(lB + (wcol + j * 16 + r16) * 64 + s * 8);
      }
#pragma unroll
      for (int i = 0; i < 4; i++)
#pragma unroll
        for (int j = 0; j < 4; j++)
          acc[i][j] = __builtin_amdgcn_mfma_f32_16x16x32_bf16(af[i], bfr[j], acc[i][j], 0, 0, 0);
    }
  }

#pragma unroll
  for (int i = 0; i < 4; i++) {
#pragma unroll
    for (int r = 0; r < 4; r++) {
      int row = rowBase + wrow + i * 16 + q * 4 + r;
#pragma unroll
      for (int j = 0; j < 4; j++) {
        int col = colBase + wcol + j * 16 + r16;
        gt[(size_t)row * 1024 + col] = f2bf(acc[i][j][r]);
      }
    }
  }
}

// ---------- driver ----------

extern "C" void kernel_launch(void* const* d_in, const int* in_sizes, int n_in,
                              void* d_out, int out_size, void* d_ws, size_t ws_size,
                              hipStream_t stream) {
  (void)in_sizes; (void)n_in; (void)out_size;

  const float* x  = (const float*)d_in[0];
  const float* Wq = (const float*)d_in[1];
  const float* bq = (const float*)d_in[2];
  const float* Wk = (const float*)d_in[3];
  // bk unused: its logit contribution is row-constant -> cancels in softmax
  const float* Wv = (const float*)d_in[5];
  const float* bv = (const float*)d_in[6];
  float* out = (float*)d_out;

  const int Nb = 4, L = 2048, D = 1024, O = 1024;
  const int M = Nb * L;  // 8192
  const float scale = 0.022097086912079608f;  // 1/sqrt(2048)

  char* ws = (char*)d_ws;
  size_t off = 0;
  unsigned short* xb  = (unsigned short*)(ws + off); off += (size_t)M * D * 2;
  unsigned short* xg  = (unsigned short*)(ws + off); off += (size_t)M * D * 2;
  unsigned short* vt  = (unsigned short*)(ws + off); off += (size_t)M * O * 2;
  unsigned short* Bp  = (unsigned short*)(ws + off); off += (size_t)2048 * D * 2; // [GT; WvT]
  unsigned short* wqb = (unsigned short*)(ws + off); off += (size_t)D * D * 2;
  unsigned short* wkb = (unsigned short*)(ws + off); off += (size_t)D * D * 2;
  unsigned short* P   = (unsigned short*)(ws + off); off += (size_t)Nb * L * L * 2;
  float* rsum  = (float*)(ws + off); off += (size_t)M * 4;
  float* zvec  = (float*)(ws + off); off += (size_t)D * 4;
  float* sbeta = (float*)(ws + off); off += (size_t)M * 4;
  if (ws_size < off) return;

  dim3 blk256(256);

  // 1: all independent prep in one launch
  prep_all<<<11528, blk256, 0, stream>>>(
      x, xb, Wq, wqb, Wk, wkb, Wv, Bp + (size_t)1024 * 1024, bq, zvec, rsum);

  // 2: GT = Wk@Wq^T into Bp rows 0..1023, plus sbeta = scale*(xb@zvec)
  gt_sbeta<<<576, blk256, 0, stream>>>(wkb, wqb, Bp, xb, zvec, sbeta, scale);

  // 3: fused [xg | v] = xb @ Bp^T ; xg plain bf16, v -> vt transposed (+bv)
  gemm64<5><<<dim3(16, 64, 1), blk256, 0, stream>>>(
      xb, Bp, nullptr, 0, 0, 0, D, D, D, 0,
      xg, vt, nullptr, bv, nullptr, 0.f);

  // 4: QK: P'[b] = exp(xg[b] @ xb[b]^T * scale + sbeta), rsum = row sums
  gemm64<1><<<dim3(16, 16, 4), blk256, 0, stream>>>(
      xg, xb, nullptr, (long long)L * D, (long long)L * D, (long long)L * L,
      D, D, D, L,
      P, nullptr, sbeta, nullptr, rsum, scale);

  // 5: PV: out[b] = (P'[b] @ vt[b]^T) / rsum
  gemm64<3><<<dim3(8, 16, 4), blk256, 0, stream>>>(
      P, vt, out, (long long)L * L, (long long)O * L, (long long)L * O,
      L, L, L, O,
      nullptr, nullptr, nullptr, nullptr, rsum, 0.f);
}